// Round 1
// baseline (4058.397 us; speedup 1.0000x reference)
//
#include <hip/hip_runtime.h>

#define BATCH 8
#define SEQ   4096
#define DIM   512

typedef __attribute__((ext_vector_type(8))) short bf16x8;
typedef __attribute__((ext_vector_type(4))) float f32x4;

__device__ __forceinline__ unsigned short f2bf(float f) {
  unsigned int u = __float_as_uint(f);
  unsigned int r = (u + 0x7fffu + ((u >> 16) & 1u)) >> 16;
  return (unsigned short)r;
}
__device__ __forceinline__ float bf2f(unsigned short s) {
  return __uint_as_float(((unsigned int)s) << 16);
}

// async global->LDS, 16B per lane; LDS dest = wave-uniform base + lane*16
__device__ __forceinline__ void gload_lds16(const void* g, void* l) {
  __builtin_amdgcn_global_load_lds(
      (const __attribute__((address_space(1))) unsigned int*)g,
      (__attribute__((address_space(3))) unsigned int*)l, 16, 0, 0);
}

// ---------------------------------------------------------------------------
// Transpose + split weights: Wt[e][d] = W[d][e] (* scale for rotation).
// ---------------------------------------------------------------------------
__global__ __launch_bounds__(256) void wt_split_kernel(
    const float* __restrict__ rot, const float* __restrict__ ent,
    unsigned short* __restrict__ wrh, unsigned short* __restrict__ wrl,
    unsigned short* __restrict__ weh, unsigned short* __restrict__ wel) {
  const float scale = 0.04419417382415922f;  // 1/sqrt(512)
  int g = blockIdx.x * 256 + threadIdx.x;
  for (int idx = g; idx < 512 * 512; idx += 128 * 256) {
    int d = idx >> 9, e = idx & 511;
    size_t o = (size_t)e * 512 + d;
    float v = rot[idx] * scale;
    unsigned short h = f2bf(v);
    wrh[o] = h; wrl[o] = f2bf(v - bf2f(h));
    float v2 = ent[idx];
    unsigned short h2 = f2bf(v2);
    weh[o] = h2; wel[o] = f2bf(v2 - bf2f(h2));
  }
}

// ---------------------------------------------------------------------------
// Transpose x: Xt[b][d][n] = x[b][n][d], bf16 hi only (PV is single-term).
// Also emits row-major bf16 split Xh/Xl (consumed by proj_both instead of
// re-reading + re-converting fp32 X 8x).
// ---------------------------------------------------------------------------
__global__ __launch_bounds__(256) void xt_split_kernel(
    const float* __restrict__ X, unsigned short* __restrict__ Th,
    unsigned short* __restrict__ Xh, unsigned short* __restrict__ Xl) {
  __shared__ float T[64][65];
  const int b = blockIdx.z, n0 = blockIdx.x * 64, d0 = blockIdx.y * 64;
  const int tid = threadIdx.x;
  for (int idx = tid; idx < 4096; idx += 256) {
    int r = idx >> 6, c = idx & 63;
    size_t gi = ((size_t)(b * SEQ + n0 + r)) * DIM + d0 + c;
    float v = X[gi];
    T[r][c] = v;
    unsigned short h = f2bf(v);
    Xh[gi] = h;
    Xl[gi] = f2bf(v - bf2f(h));
  }
  __syncthreads();
  for (int idx = tid; idx < 4096; idx += 256) {
    int r = idx >> 6, c = idx & 63;  // r: d, c: n
    size_t o = ((size_t)(b * DIM + d0 + r)) * SEQ + n0 + c;
    Th[o] = f2bf(T[c][r]);
  }
}

// ---------------------------------------------------------------------------
// Fused projection: Q = X@rot*scale, K = X@ent via bf16-split MFMA (3 terms).
// Reads pre-split Xh/Xl (no per-block fp32->bf16 conversion).
// Grid = (rowTiles=512, colTiles=8): the 8 col-tiles sharing an X row-tile
// are ids y*512 apart -> same XCD (id%8 == rowTile%8) -> X fetched once, not 8x.
// ---------------------------------------------------------------------------
__global__ __launch_bounds__(256, 2) void proj_both(
    const unsigned short* __restrict__ Xh, const unsigned short* __restrict__ Xl,
    const unsigned short* __restrict__ wrh, const unsigned short* __restrict__ wrl,
    const unsigned short* __restrict__ weh, const unsigned short* __restrict__ wel,
    unsigned short* __restrict__ qh, unsigned short* __restrict__ ql,
    unsigned short* __restrict__ kh, unsigned short* __restrict__ kl) {
  const int tid = threadIdx.x;
  const int w = tid >> 6, lane = tid & 63, l15 = lane & 15, quad = lane >> 4;
  const int rowBase = blockIdx.x * 64 + (w & 1) * 32;
  const int colBase = blockIdx.y * 64 + (w >> 1) * 32;
  f32x4 qa[2][2] = {}, ka[2][2] = {};
  const unsigned short *xph[2], *xpl[2];
  const unsigned short *rh[2], *rl[2], *eh[2], *el[2];
#pragma unroll
  for (int mi = 0; mi < 2; ++mi) {
    size_t o = (size_t)(rowBase + mi * 16 + l15) * DIM + quad * 8;
    xph[mi] = Xh + o; xpl[mi] = Xl + o;
  }
#pragma unroll
  for (int ni = 0; ni < 2; ++ni) {
    size_t o = (size_t)(colBase + ni * 16 + l15) * DIM + quad * 8;
    rh[ni] = wrh + o; rl[ni] = wrl + o; eh[ni] = weh + o; el[ni] = wel + o;
  }
  for (int d0 = 0; d0 < DIM; d0 += 32) {
    bf16x8 ah[2], al[2];
#pragma unroll
    for (int mi = 0; mi < 2; ++mi) {
      ah[mi] = *(const bf16x8*)(xph[mi] + d0);
      al[mi] = *(const bf16x8*)(xpl[mi] + d0);
    }
#pragma unroll
    for (int ni = 0; ni < 2; ++ni) {
      bf16x8 bh = *(const bf16x8*)(rh[ni] + d0);
      bf16x8 bl = *(const bf16x8*)(rl[ni] + d0);
      bf16x8 ch = *(const bf16x8*)(eh[ni] + d0);
      bf16x8 cl = *(const bf16x8*)(el[ni] + d0);
#pragma unroll
      for (int mi = 0; mi < 2; ++mi) {
        qa[mi][ni] = __builtin_amdgcn_mfma_f32_16x16x32_bf16(ah[mi], bh, qa[mi][ni], 0, 0, 0);
        qa[mi][ni] = __builtin_amdgcn_mfma_f32_16x16x32_bf16(ah[mi], bl, qa[mi][ni], 0, 0, 0);
        qa[mi][ni] = __builtin_amdgcn_mfma_f32_16x16x32_bf16(al[mi], bh, qa[mi][ni], 0, 0, 0);
        ka[mi][ni] = __builtin_amdgcn_mfma_f32_16x16x32_bf16(ah[mi], ch, ka[mi][ni], 0, 0, 0);
        ka[mi][ni] = __builtin_amdgcn_mfma_f32_16x16x32_bf16(ah[mi], cl, ka[mi][ni], 0, 0, 0);
        ka[mi][ni] = __builtin_amdgcn_mfma_f32_16x16x32_bf16(al[mi], ch, ka[mi][ni], 0, 0, 0);
      }
    }
  }
#pragma unroll
  for (int mi = 0; mi < 2; ++mi)
#pragma unroll
    for (int ni = 0; ni < 2; ++ni)
#pragma unroll
      for (int r = 0; r < 4; ++r) {
        int row = rowBase + mi * 16 + quad * 4 + r;
        int col = colBase + ni * 16 + l15;
        size_t o = (size_t)row * DIM + col;
        float v = qa[mi][ni][r];
        unsigned short h = f2bf(v);
        qh[o] = h; ql[o] = f2bf(v - bf2f(h));
        float v2 = ka[mi][ni][r];
        unsigned short h2 = f2bf(v2);
        kh[o] = h2; kl[o] = f2bf(v2 - bf2f(h2));
      }
}

// ---------------------------------------------------------------------------
// Flash attention, BQ=64, BK=128 per online-softmax iteration, 4 waves.
//   - Wave w owns q-subtile w (16 rows): Q hi/lo held in REGISTERS for the
//     whole block (read from HBM once, was 32x) -> softmax fully wave-local.
//   - K hi/lo staged via global_load_lds (16B) in 32-d chunks, double-buffered,
//     pre-swizzled global source so LDS stays linear; 16 barriers / 128 k.
//   - P (bf16) transposed through a 64x128 XOR-swizzled LDS buffer that
//     ALIASES stage buf1 (dead during softmax+PV) -> LDS = 33 KB -> 4 blk/CU.
//   - Next iteration's chunk 0 is prefetched during PV.
//   - grid (BATCH, 64, splits): linear id % 8 == batch -> XCD-local K/X streams.
//   - split-K: z=0 writes raw O to out, z=1 to Opart; merge_kernel combines.
// ---------------------------------------------------------------------------
__global__ __launch_bounds__(256, 4) void attn_mfma(
    const unsigned short* __restrict__ Qh, const unsigned short* __restrict__ Ql,
    const unsigned short* __restrict__ Kh, const unsigned short* __restrict__ Kl,
    const unsigned short* __restrict__ Xth, float* __restrict__ out,
    float* __restrict__ Opart, float* __restrict__ Mp, float* __restrict__ Lp) {
  // stage[buf]: [Kh 128x32 (4096 shorts) | Kl 128x32 (4096 shorts)] = 16 KiB
  __shared__ short stage[2][8192];            // 32 KiB
  __shared__ float al_s[64], l_s[64];
  unsigned short* const PsH = (unsigned short*)&stage[1][0];  // 64x128 swizzled

  const int tid = threadIdx.x;
  const int w = tid >> 6, lane = tid & 63, l15 = lane & 15, quad = lane >> 4;
  const int b = blockIdx.x, q0 = blockIdx.y * 64;
  const int iters = (SEQ / 128) / gridDim.z;
  const int kbase = blockIdx.z * iters * 128;
  const int dbase = w * 128;  // PV output d-slice per wave

  // ---- Q fragments in registers: wave w owns rows q0 + w*16 + [0,16) ----
  bf16x8 qfh[16], qfl[16];
  {
    const size_t qrow = (size_t)(b * SEQ + q0 + w * 16 + l15) * DIM + quad * 8;
#pragma unroll
    for (int c = 0; c < 16; ++c) {
      qfh[c] = *(const bf16x8*)(Qh + qrow + c * 32);
      qfl[c] = *(const bf16x8*)(Ql + qrow + c * 32);
    }
  }

  // ---- staging map: 4 x 16B per thread per chunk, LDS linear in lane ----
  // short-offset so = j*2048 + w*512 + lane*8; plane = so>>12 (0=Kh,1=Kl);
  // within plane: r = (so&4095)>>5 (row 0..127), cb = ((so&4095)>>3)&3,
  // global 16B-block clog = cb ^ (r&3)  (pre-swizzled source, linear LDS).
  const unsigned short* ksrc[4];
  int ldsoff[4];
  {
#pragma unroll
    for (int j = 0; j < 4; ++j) {
      int so = j * 2048 + w * 512 + lane * 8;
      int plane = so >> 12;
      int off = so & 4095;
      int r = off >> 5;
      int cb = (off >> 3) & 3;
      int clog = cb ^ (r & 3);
      ksrc[j] = (plane ? Kl : Kh) + (size_t)(b * SEQ + r) * DIM + clog * 8;
      ldsoff[j] = j * 2048 + w * 512;  // wave-uniform LDS base (shorts)
    }
  }
  auto STAGE = [&](int bsel, int krow, int cc) {
#pragma unroll
    for (int j = 0; j < 4; ++j)
      gload_lds16(ksrc[j] + (size_t)krow * DIM + cc * 32,
                  &stage[bsel][ldsoff[j]]);
  };

  f32x4 Of[4][8] = {};
  float m_r[4], l_r[4];
#pragma unroll
  for (int r = 0; r < 4; ++r) { m_r[r] = -3.0e38f; l_r[r] = 0.0f; }

  // prologue: stage chunk 0 of first iteration into buf0
  STAGE(0, kbase, 0);
  __syncthreads();

  for (int t = 0; t < iters; ++t) {
    const int k0 = kbase + t * 128;
    f32x4 sa[8] = {};  // S accum: wave's 16 q-rows x 8 k-subtiles (128 k)

    // ---- S = Q K^T over 16 chunks of 32 d, double-buffered ----
#pragma unroll
    for (int c = 0; c < 16; ++c) {
      if (c < 15) STAGE((c + 1) & 1, k0, c + 1);
      const short* bufp = &stage[c & 1][0];
      const int cq = (quad ^ (l15 & 3)) * 8;  // (s*16) keeps kr&3 == l15&3
#pragma unroll
      for (int s = 0; s < 8; ++s) {
        const int kr = s * 16 + l15;
        bf16x8 bh = *(const bf16x8*)(bufp + kr * 32 + cq);
        bf16x8 bl = *(const bf16x8*)(bufp + 4096 + kr * 32 + cq);
        sa[s] = __builtin_amdgcn_mfma_f32_16x16x32_bf16(qfh[c], bh, sa[s], 0, 0, 0);
        sa[s] = __builtin_amdgcn_mfma_f32_16x16x32_bf16(qfh[c], bl, sa[s], 0, 0, 0);
        sa[s] = __builtin_amdgcn_mfma_f32_16x16x32_bf16(qfl[c], bh, sa[s], 0, 0, 0);
      }
      __syncthreads();  // drains staged chunk c+1; last one protects PsH alias
    }

    // ---- wave-local online softmax (rows = w*16 + quad*4 + r) ----
    float al_r[4];
#pragma unroll
    for (int r = 0; r < 4; ++r) {
      float v = sa[0][r];
#pragma unroll
      for (int s = 1; s < 8; ++s) v = fmaxf(v, sa[s][r]);
#pragma unroll
      for (int off = 1; off < 16; off <<= 1) v = fmaxf(v, __shfl_xor(v, off, 64));
      float mn = fmaxf(m_r[r], v);
      al_r[r] = __expf(m_r[r] - mn);
      m_r[r] = mn;
    }
#pragma unroll
    for (int r = 0; r < 4; ++r) {
      const int row = w * 16 + quad * 4 + r, rx = row & 15;
      float sum = 0.0f;
#pragma unroll
      for (int s = 0; s < 8; ++s) {
        float p = __expf(sa[s][r] - m_r[r]);
        sum += p;
        const int col = s * 16 + l15;
        PsH[row * 128 + ((col >> 3) ^ rx) * 8 + (col & 7)] = f2bf(p);
      }
#pragma unroll
      for (int off = 1; off < 16; off <<= 1) sum += __shfl_xor(sum, off, 64);
      l_r[r] = l_r[r] * al_r[r] + sum;
    }
    if (l15 == 0) {
#pragma unroll
      for (int r = 0; r < 4; ++r) al_s[w * 16 + quad * 4 + r] = al_r[r];
    }
    __syncthreads();  // PsH + al_s visible to all waves

    // ---- O = O*alpha + P @ x ; wave handles d-slice [dbase, dbase+128) ----
    float alv[4][4];
#pragma unroll
    for (int qt = 0; qt < 4; ++qt)
#pragma unroll
      for (int r = 0; r < 4; ++r) alv[qt][r] = al_s[qt * 16 + quad * 4 + r];
#pragma unroll
    for (int qt = 0; qt < 4; ++qt)
#pragma unroll
      for (int nt = 0; nt < 8; ++nt)
#pragma unroll
        for (int r = 0; r < 4; ++r) Of[qt][nt][r] *= alv[qt][r];

    // prefetch next iteration's chunk 0 into buf0 (free since chunk 14)
    if (t + 1 < iters) STAGE(0, k0 + 128, 0);

#pragma unroll
    for (int ks = 0; ks < 4; ++ks) {
      bf16x8 Ph[4];
#pragma unroll
      for (int qt = 0; qt < 4; ++qt) {
        const int prow = qt * 16 + l15;
        const int sb = (ks * 4 + quad) ^ l15;
        Ph[qt] = *(const bf16x8*)(PsH + prow * 128 + sb * 8);
      }
      bf16x8 xf[8];
#pragma unroll
      for (int nt = 0; nt < 8; ++nt) {
        const size_t xo =
            ((size_t)(b * DIM + dbase + nt * 16 + l15)) * SEQ + k0 + ks * 32 + quad * 8;
        xf[nt] = *(const bf16x8*)(Xth + xo);
      }
#pragma unroll
      for (int nt = 0; nt < 8; ++nt)
#pragma unroll
        for (int qt = 0; qt < 4; ++qt)
          Of[qt][nt] = __builtin_amdgcn_mfma_f32_16x16x32_bf16(Ph[qt], xf[nt], Of[qt][nt], 0, 0, 0);
    }
    __syncthreads();  // PsH free for next iter's staging; buf0 drain complete
  }

  // ---- epilogue ----
  if (l15 == 0) {
#pragma unroll
    for (int r = 0; r < 4; ++r) l_s[w * 16 + quad * 4 + r] = l_r[r];
    if (gridDim.z > 1) {
      size_t ri = (size_t)blockIdx.z * (BATCH * SEQ) + (size_t)b * SEQ + q0 + w * 16 + quad * 4;
#pragma unroll
      for (int r = 0; r < 4; ++r) { Mp[ri + r] = m_r[r]; Lp[ri + r] = l_r[r]; }
    }
  }
  __syncthreads();

  if (gridDim.z == 1) {
    float inv[4][4];
#pragma unroll
    for (int qt = 0; qt < 4; ++qt)
#pragma unroll
      for (int r = 0; r < 4; ++r) inv[qt][r] = 1.0f / l_s[qt * 16 + quad * 4 + r];
#pragma unroll
    for (int qt = 0; qt < 4; ++qt)
#pragma unroll
      for (int r = 0; r < 4; ++r) {
        const size_t ro = ((size_t)(b * SEQ + q0 + qt * 16 + quad * 4 + r)) * DIM + dbase;
#pragma unroll
        for (int nt = 0; nt < 8; ++nt) out[ro + nt * 16 + l15] = Of[qt][nt][r] * inv[qt][r];
      }
  } else {
    float* Ob = (blockIdx.z == 0) ? out : Opart;
#pragma unroll
    for (int qt = 0; qt < 4; ++qt)
#pragma unroll
      for (int r = 0; r < 4; ++r) {
        const size_t ro = ((size_t)(b * SEQ + q0 + qt * 16 + quad * 4 + r)) * DIM + dbase;
#pragma unroll
        for (int nt = 0; nt < 8; ++nt) Ob[ro + nt * 16 + l15] = Of[qt][nt][r];
      }
  }
}

// ---------------------------------------------------------------------------
// Merge split-K partials: z=0 partial lives in `out`, z=1 in Opart.
// out = (a0*O0 + a1*O1) / (a0*l0 + a1*l1).
// ---------------------------------------------------------------------------
__global__ __launch_bounds__(256) void merge_kernel(
    float* __restrict__ out, const float* __restrict__ Op,
    const float* __restrict__ Mp, const float* __restrict__ Lp) {
  const int NR = BATCH * SEQ;
  size_t e = ((size_t)blockIdx.x * 256 + threadIdx.x) * 4;
  int row = (int)(e >> 9);
  float m0 = Mp[row], m1 = Mp[NR + row];
  float l0 = Lp[row], l1 = Lp[NR + row];
  float m = fmaxf(m0, m1);
  float a0 = __expf(m0 - m), a1 = __expf(m1 - m);
  float inv = 1.0f / (a0 * l0 + a1 * l1);
  float4 o0 = *(const float4*)(out + e);
  float4 o1 = *(const float4*)(Op + e);
  float4 r;
  r.x = (a0 * o0.x + a1 * o1.x) * inv;
  r.y = (a0 * o0.y + a1 * o1.y) * inv;
  r.z = (a0 * o0.z + a1 * o1.z) * inv;
  r.w = (a0 * o0.w + a1 * o1.w) * inv;
  *(float4*)(out + e) = r;
}

// ---------------------------------------------------------------------------
extern "C" void kernel_launch(void* const* d_in, const int* in_sizes, int n_in,
                              void* d_out, int out_size, void* d_ws,
                              size_t ws_size, hipStream_t stream) {
  const float* x   = (const float*)d_in[0];
  const float* rot = (const float*)d_in[1];
  const float* ent = (const float*)d_in[2];
  float* out = (float*)d_out;

  const size_t NE = (size_t)BATCH * SEQ * DIM;  // 16,777,216
  unsigned short* qh  = (unsigned short*)d_ws;
  unsigned short* ql  = qh + NE;
  unsigned short* kh  = ql + NE;
  unsigned short* kl  = kh + NE;
  unsigned short* xth = kl + NE;
  unsigned short* xh  = xth + NE;
  unsigned short* xl  = xh + NE;
  unsigned short* wrh = xl + NE;
  unsigned short* wrl = wrh + 262144;
  unsigned short* weh = wrl + 262144;
  unsigned short* wel = weh + 262144;
  float* Opart = (float*)(wel + 262144);         // NE floats (z=1 partial)
  float* Mp    = Opart + NE;                     // 2 * 32768
  float* Lp    = Mp + 2 * (BATCH * SEQ);

  // 7NE*2 + NE*4 == old 5NE*2 + 2NE*4  -> identical workspace requirement
  const size_t need2 =
      (7 * NE + 4 * 262144) * sizeof(unsigned short) +
      (NE + 4 * (size_t)(BATCH * SEQ)) * sizeof(float);
  const int splits = (ws_size >= need2) ? 2 : 1;

  wt_split_kernel<<<128, 256, 0, stream>>>(rot, ent, wrh, wrl, weh, wel);
  xt_split_kernel<<<dim3(SEQ / 64, DIM / 64, BATCH), 256, 0, stream>>>(x, xth, xh, xl);
  proj_both<<<dim3(BATCH * SEQ / 64, DIM / 64), 256, 0, stream>>>(
      xh, xl, wrh, wrl, weh, wel, qh, ql, kh, kl);

  attn_mfma<<<dim3(BATCH, SEQ / 64, splits), 256, 0, stream>>>(
      qh, ql, kh, kl, xth, out, Opart, Mp, Lp);
  if (splits == 2) {
    merge_kernel<<<(unsigned)(NE / 1024), 256, 0, stream>>>(out, Opart, Mp, Lp);
  }
}

// Round 2
// 1745.322 us; speedup vs baseline: 2.3253x; 2.3253x over previous
//
#include <hip/hip_runtime.h>

#define BATCH 8
#define SEQ   4096
#define DIM   512

typedef __attribute__((ext_vector_type(8))) short bf16x8;
typedef __attribute__((ext_vector_type(4))) float f32x4;

__device__ __forceinline__ unsigned short f2bf(float f) {
  unsigned int u = __float_as_uint(f);
  unsigned int r = (u + 0x7fffu + ((u >> 16) & 1u)) >> 16;
  return (unsigned short)r;
}
__device__ __forceinline__ float bf2f(unsigned short s) {
  return __uint_as_float(((unsigned int)s) << 16);
}

// async global->LDS, 16B per lane; LDS dest = wave-uniform base + lane*16
__device__ __forceinline__ void gload_lds16(const void* g, void* l) {
  __builtin_amdgcn_global_load_lds(
      (const __attribute__((address_space(1))) unsigned int*)g,
      (__attribute__((address_space(3))) unsigned int*)l, 16, 0, 0);
}

// ---------------------------------------------------------------------------
// Transpose + split weights: Wt[e][d] = W[d][e] (* scale for rotation).
// ---------------------------------------------------------------------------
__global__ __launch_bounds__(256) void wt_split_kernel(
    const float* __restrict__ rot, const float* __restrict__ ent,
    unsigned short* __restrict__ wrh, unsigned short* __restrict__ wrl,
    unsigned short* __restrict__ weh, unsigned short* __restrict__ wel) {
  const float scale = 0.04419417382415922f;  // 1/sqrt(512)
  int g = blockIdx.x * 256 + threadIdx.x;
  for (int idx = g; idx < 512 * 512; idx += 128 * 256) {
    int d = idx >> 9, e = idx & 511;
    size_t o = (size_t)e * 512 + d;
    float v = rot[idx] * scale;
    unsigned short h = f2bf(v);
    wrh[o] = h; wrl[o] = f2bf(v - bf2f(h));
    float v2 = ent[idx];
    unsigned short h2 = f2bf(v2);
    weh[o] = h2; wel[o] = f2bf(v2 - bf2f(h2));
  }
}

// ---------------------------------------------------------------------------
// Transpose x: Xt[b][d][n] = x[b][n][d], bf16 hi only (PV is single-term).
// Also emits row-major bf16 split Xh/Xl (consumed by proj_both).
// ---------------------------------------------------------------------------
__global__ __launch_bounds__(256) void xt_split_kernel(
    const float* __restrict__ X, unsigned short* __restrict__ Th,
    unsigned short* __restrict__ Xh, unsigned short* __restrict__ Xl) {
  __shared__ float T[64][65];
  const int b = blockIdx.z, n0 = blockIdx.x * 64, d0 = blockIdx.y * 64;
  const int tid = threadIdx.x;
  for (int idx = tid; idx < 4096; idx += 256) {
    int r = idx >> 6, c = idx & 63;
    size_t gi = ((size_t)(b * SEQ + n0 + r)) * DIM + d0 + c;
    float v = X[gi];
    T[r][c] = v;
    unsigned short h = f2bf(v);
    Xh[gi] = h;
    Xl[gi] = f2bf(v - bf2f(h));
  }
  __syncthreads();
  for (int idx = tid; idx < 4096; idx += 256) {
    int r = idx >> 6, c = idx & 63;  // r: d, c: n
    size_t o = ((size_t)(b * DIM + d0 + r)) * SEQ + n0 + c;
    Th[o] = f2bf(T[c][r]);
  }
}

// ---------------------------------------------------------------------------
// Fused projection: Q = X@rot*scale, K = X@ent via bf16-split MFMA (3 terms).
// Grid = (rowTiles=512, colTiles=8): col-tiles sharing an X row-tile land on
// the same XCD (id%8 == rowTile%8) -> X row-panel fetched once per XCD.
// ---------------------------------------------------------------------------
__global__ __launch_bounds__(256, 2) void proj_both(
    const unsigned short* __restrict__ Xh, const unsigned short* __restrict__ Xl,
    const unsigned short* __restrict__ wrh, const unsigned short* __restrict__ wrl,
    const unsigned short* __restrict__ weh, const unsigned short* __restrict__ wel,
    unsigned short* __restrict__ qh, unsigned short* __restrict__ ql,
    unsigned short* __restrict__ kh, unsigned short* __restrict__ kl) {
  const int tid = threadIdx.x;
  const int w = tid >> 6, lane = tid & 63, l15 = lane & 15, quad = lane >> 4;
  const int rowBase = blockIdx.x * 64 + (w & 1) * 32;
  const int colBase = blockIdx.y * 64 + (w >> 1) * 32;
  f32x4 qa[2][2] = {}, ka[2][2] = {};
  const unsigned short *xph[2], *xpl[2];
  const unsigned short *rh[2], *rl[2], *eh[2], *el[2];
#pragma unroll
  for (int mi = 0; mi < 2; ++mi) {
    size_t o = (size_t)(rowBase + mi * 16 + l15) * DIM + quad * 8;
    xph[mi] = Xh + o; xpl[mi] = Xl + o;
  }
#pragma unroll
  for (int ni = 0; ni < 2; ++ni) {
    size_t o = (size_t)(colBase + ni * 16 + l15) * DIM + quad * 8;
    rh[ni] = wrh + o; rl[ni] = wrl + o; eh[ni] = weh + o; el[ni] = wel + o;
  }
  for (int d0 = 0; d0 < DIM; d0 += 32) {
    bf16x8 ah[2], al[2];
#pragma unroll
    for (int mi = 0; mi < 2; ++mi) {
      ah[mi] = *(const bf16x8*)(xph[mi] + d0);
      al[mi] = *(const bf16x8*)(xpl[mi] + d0);
    }
#pragma unroll
    for (int ni = 0; ni < 2; ++ni) {
      bf16x8 bh = *(const bf16x8*)(rh[ni] + d0);
      bf16x8 bl = *(const bf16x8*)(rl[ni] + d0);
      bf16x8 ch = *(const bf16x8*)(eh[ni] + d0);
      bf16x8 cl = *(const bf16x8*)(el[ni] + d0);
#pragma unroll
      for (int mi = 0; mi < 2; ++mi) {
        qa[mi][ni] = __builtin_amdgcn_mfma_f32_16x16x32_bf16(ah[mi], bh, qa[mi][ni], 0, 0, 0);
        qa[mi][ni] = __builtin_amdgcn_mfma_f32_16x16x32_bf16(ah[mi], bl, qa[mi][ni], 0, 0, 0);
        qa[mi][ni] = __builtin_amdgcn_mfma_f32_16x16x32_bf16(al[mi], bh, qa[mi][ni], 0, 0, 0);
        ka[mi][ni] = __builtin_amdgcn_mfma_f32_16x16x32_bf16(ah[mi], ch, ka[mi][ni], 0, 0, 0);
        ka[mi][ni] = __builtin_amdgcn_mfma_f32_16x16x32_bf16(ah[mi], cl, ka[mi][ni], 0, 0, 0);
        ka[mi][ni] = __builtin_amdgcn_mfma_f32_16x16x32_bf16(al[mi], ch, ka[mi][ni], 0, 0, 0);
      }
    }
  }
#pragma unroll
  for (int mi = 0; mi < 2; ++mi)
#pragma unroll
    for (int ni = 0; ni < 2; ++ni)
#pragma unroll
      for (int r = 0; r < 4; ++r) {
        int row = rowBase + mi * 16 + quad * 4 + r;
        int col = colBase + ni * 16 + l15;
        size_t o = (size_t)row * DIM + col;
        float v = qa[mi][ni][r];
        unsigned short h = f2bf(v);
        qh[o] = h; ql[o] = f2bf(v - bf2f(h));
        float v2 = ka[mi][ni][r];
        unsigned short h2 = f2bf(v2);
        kh[o] = h2; kl[o] = f2bf(v2 - bf2f(h2));
      }
}

// ---------------------------------------------------------------------------
// Flash attention, BQ=32, BK=128, 4 waves, 256 threads.
//   Register budget is the design driver (gfx950 unified VGPR+AGPR file):
//   Of[2][8]=64 acc + sa[4]=16 + temps ~70  =>  ~150 regs -> 3 waves/SIMD.
//   - Wave (wq=w&1, wk=w>>1): q-subtile wq (16 rows), k-halftile wk (64 cols).
//   - Q read per-chunk from global (block Q slice = 64 KB -> L1/L2 hits).
//   - K hi+lo staged via global_load_lds (16B), 32-d chunks, double-buffered,
//     pre-swizzled global source, linear LDS. 16 barriers / 128 k.
//   - P bf16 (32x128, XOR-swizzled) aliases stage buf1 -> LDS 33 KB.
//   - Next iteration's chunk 0 prefetched at chunk 15.
//   - grid (BATCH, 128, z): id%8 == batch -> XCD-local K/Xt streams.
// ---------------------------------------------------------------------------
__global__ __launch_bounds__(256, 2) void attn_mfma(
    const unsigned short* __restrict__ Qh, const unsigned short* __restrict__ Ql,
    const unsigned short* __restrict__ Kh, const unsigned short* __restrict__ Kl,
    const unsigned short* __restrict__ Xth, float* __restrict__ out,
    float* __restrict__ Opart, float* __restrict__ Mp, float* __restrict__ Lp) {
  // stage[buf]: [Kh 128x32 (4096 sh) | Kl 128x32 (4096 sh)] = 16 KiB each
  __shared__ short stage[2][8192];  // 32 KiB
  __shared__ float red1[32][2], red2[32][2], al_s[32], l_s[32];
  unsigned short* const PsH = (unsigned short*)&stage[1][0];  // 32x128 swizzled

  const int tid = threadIdx.x;
  const int w = tid >> 6, lane = tid & 63, l15 = lane & 15, quad = lane >> 4;
  const int wq = w & 1, wk = w >> 1;
  const int b = blockIdx.x, q0 = blockIdx.y * 32;
  const int iters = (SEQ / 128) / gridDim.z;
  const int kbase = blockIdx.z * iters * 128;
  const int dbase = w * 128;  // PV output d-slice per wave

  // ---- Q row pointers (per-chunk direct global reads, L1/L2-resident) ----
  const size_t qoff = (size_t)(b * SEQ + q0 + wq * 16 + l15) * DIM + quad * 8;
  const unsigned short* qph = Qh + qoff;
  const unsigned short* qpl = Ql + qoff;

  // ---- K staging map: thread stages 4 x 16B per chunk, LDS linear ----
  // thread slot j: lds byte = j*4096 + tid*16; plane = j>>1 (0=Kh,1=Kl);
  // row = (j&1)*64 + tid/4; phys 16B-block = tid&3; src block = (tid&3)^(row&3).
  const int r0 = tid >> 2;
  const int clog = (tid & 3) ^ (r0 & 3);
  const unsigned short* kpl[2] = {Kh + (size_t)b * SEQ * DIM,
                                  Kl + (size_t)b * SEQ * DIM};
  auto STAGE = [&](int bsel, int krow, int cc) {
#pragma unroll
    for (int j = 0; j < 4; ++j) {
      const int row = (j & 1) * 64 + r0;
      gload_lds16(kpl[j >> 1] + (size_t)(krow + row) * DIM + cc * 32 + clog * 8,
                  &stage[bsel][j * 2048 + w * 512]);
    }
  };

  f32x4 Of[2][8] = {};
  float m_r[4], l_r[4];
#pragma unroll
  for (int r = 0; r < 4; ++r) { m_r[r] = -3.0e38f; l_r[r] = 0.0f; }

  STAGE(0, kbase, 0);
  __syncthreads();

  for (int t = 0; t < iters; ++t) {
    const int k0 = kbase + t * 128;
    f32x4 sa[4] = {};

    // ---- S = Q K^T over 16 chunks of 32 d, double-buffered ----
#pragma unroll
    for (int c = 0; c < 16; ++c) {
      if (c < 15) STAGE((c + 1) & 1, k0, c + 1);
      else if (t + 1 < iters) STAGE(0, k0 + 128, 0);  // prefetch next iter
      bf16x8 ah = *(const bf16x8*)(qph + c * 32);
      bf16x8 al = *(const bf16x8*)(qpl + c * 32);
      const short* bufp = &stage[c & 1][0];
      const int cq = (quad ^ (l15 & 3)) * 8;  // kr&3 == l15&3 below
#pragma unroll
      for (int s = 0; s < 4; ++s) {
        const int kr = wk * 64 + s * 16 + l15;
        bf16x8 bh = *(const bf16x8*)(bufp + kr * 32 + cq);
        bf16x8 bl = *(const bf16x8*)(bufp + 4096 + kr * 32 + cq);
        sa[s] = __builtin_amdgcn_mfma_f32_16x16x32_bf16(ah, bh, sa[s], 0, 0, 0);
        sa[s] = __builtin_amdgcn_mfma_f32_16x16x32_bf16(ah, bl, sa[s], 0, 0, 0);
        sa[s] = __builtin_amdgcn_mfma_f32_16x16x32_bf16(al, bh, sa[s], 0, 0, 0);
      }
      __syncthreads();  // drains staged chunk; last one frees buf1 for PsH
    }

    // ---- online softmax: wave owns rows wq*16 + quad*4 + r (k-half wk) ----
    float pm[4];
#pragma unroll
    for (int r = 0; r < 4; ++r) {
      float v = fmaxf(fmaxf(sa[0][r], sa[1][r]), fmaxf(sa[2][r], sa[3][r]));
#pragma unroll
      for (int off = 1; off < 16; off <<= 1) v = fmaxf(v, __shfl_xor(v, off, 64));
      pm[r] = v;
    }
    if (l15 == 0) {
#pragma unroll
      for (int r = 0; r < 4; ++r) red1[wq * 16 + quad * 4 + r][wk] = pm[r];
    }
    __syncthreads();  // B1
    float al_r[4];
#pragma unroll
    for (int r = 0; r < 4; ++r) {
      const int row = wq * 16 + quad * 4 + r;
      float mn = fmaxf(m_r[r], fmaxf(red1[row][0], red1[row][1]));
      al_r[r] = __expf(m_r[r] - mn);
      m_r[r] = mn;
    }
#pragma unroll
    for (int r = 0; r < 4; ++r) {
      const int row = wq * 16 + quad * 4 + r, rx = row & 15;
      float sum = 0.0f;
#pragma unroll
      for (int s = 0; s < 4; ++s) {
        float p = __expf(sa[s][r] - m_r[r]);
        sum += p;
        const int col = wk * 64 + s * 16 + l15;
        PsH[row * 128 + ((col >> 3) ^ rx) * 8 + (col & 7)] = f2bf(p);
      }
#pragma unroll
      for (int off = 1; off < 16; off <<= 1) sum += __shfl_xor(sum, off, 64);
      if (l15 == 0) {
        red2[row][wk] = sum;
        if (wk == 0) al_s[row] = al_r[r];
      }
    }
    __syncthreads();  // B2: PsH + al_s + red2 visible
#pragma unroll
    for (int r = 0; r < 4; ++r) {
      const int row = wq * 16 + quad * 4 + r;
      l_r[r] = l_r[r] * al_r[r] + red2[row][0] + red2[row][1];
    }

    // ---- O = O*alpha + P @ x ; wave d-slice [dbase, dbase+128) ----
    float alv[2][4];
#pragma unroll
    for (int qt = 0; qt < 2; ++qt)
#pragma unroll
      for (int r = 0; r < 4; ++r) alv[qt][r] = al_s[qt * 16 + quad * 4 + r];
#pragma unroll
    for (int qt = 0; qt < 2; ++qt)
#pragma unroll
      for (int nt = 0; nt < 8; ++nt)
#pragma unroll
        for (int r = 0; r < 4; ++r) Of[qt][nt][r] *= alv[qt][r];

    const unsigned short* Xb =
        Xth + ((size_t)(b * DIM + dbase) + l15) * SEQ + k0 + quad * 8;
#pragma unroll
    for (int ks = 0; ks < 4; ++ks) {
      bf16x8 Ph[2];
#pragma unroll
      for (int qt = 0; qt < 2; ++qt) {
        const int prow = qt * 16 + l15;
        const int sb = (ks * 4 + quad) ^ l15;
        Ph[qt] = *(const bf16x8*)(PsH + prow * 128 + sb * 8);
      }
#pragma unroll
      for (int nh = 0; nh < 2; ++nh) {  // two halves of 4 to cap reg peak
        bf16x8 xf[4];
#pragma unroll
        for (int i = 0; i < 4; ++i)
          xf[i] = *(const bf16x8*)(Xb + (size_t)((nh * 4 + i) * 16) * SEQ + ks * 32);
#pragma unroll
        for (int i = 0; i < 4; ++i)
#pragma unroll
          for (int qt = 0; qt < 2; ++qt)
            Of[qt][nh * 4 + i] = __builtin_amdgcn_mfma_f32_16x16x32_bf16(
                Ph[qt], xf[i], Of[qt][nh * 4 + i], 0, 0, 0);
      }
    }
    __syncthreads();  // B3: PsH reads done before next iter stages buf1
  }

  // ---- epilogue ----
  if (wk == 0 && l15 == 0) {
#pragma unroll
    for (int r = 0; r < 4; ++r) l_s[wq * 16 + quad * 4 + r] = l_r[r];
    if (gridDim.z > 1) {
      size_t ri = (size_t)blockIdx.z * (BATCH * SEQ) + (size_t)b * SEQ + q0 +
                  wq * 16 + quad * 4;
#pragma unroll
      for (int r = 0; r < 4; ++r) { Mp[ri + r] = m_r[r]; Lp[ri + r] = l_r[r]; }
    }
  }
  __syncthreads();

  if (gridDim.z == 1) {
    float inv[2][4];
#pragma unroll
    for (int qt = 0; qt < 2; ++qt)
#pragma unroll
      for (int r = 0; r < 4; ++r) inv[qt][r] = 1.0f / l_s[qt * 16 + quad * 4 + r];
#pragma unroll
    for (int qt = 0; qt < 2; ++qt)
#pragma unroll
      for (int r = 0; r < 4; ++r) {
        const size_t ro =
            ((size_t)(b * SEQ + q0 + qt * 16 + quad * 4 + r)) * DIM + dbase;
#pragma unroll
        for (int nt = 0; nt < 8; ++nt)
          out[ro + nt * 16 + l15] = Of[qt][nt][r] * inv[qt][r];
      }
  } else {
    float* Ob = (blockIdx.z == 0) ? out : Opart;
#pragma unroll
    for (int qt = 0; qt < 2; ++qt)
#pragma unroll
      for (int r = 0; r < 4; ++r) {
        const size_t ro =
            ((size_t)(b * SEQ + q0 + qt * 16 + quad * 4 + r)) * DIM + dbase;
#pragma unroll
        for (int nt = 0; nt < 8; ++nt) Ob[ro + nt * 16 + l15] = Of[qt][nt][r];
      }
  }
}

// ---------------------------------------------------------------------------
// Merge split-K partials: z=0 partial lives in `out`, z=1 in Opart.
// ---------------------------------------------------------------------------
__global__ __launch_bounds__(256) void merge_kernel(
    float* __restrict__ out, const float* __restrict__ Op,
    const float* __restrict__ Mp, const float* __restrict__ Lp) {
  const int NR = BATCH * SEQ;
  size_t e = ((size_t)blockIdx.x * 256 + threadIdx.x) * 4;
  int row = (int)(e >> 9);
  float m0 = Mp[row], m1 = Mp[NR + row];
  float l0 = Lp[row], l1 = Lp[NR + row];
  float m = fmaxf(m0, m1);
  float a0 = __expf(m0 - m), a1 = __expf(m1 - m);
  float inv = 1.0f / (a0 * l0 + a1 * l1);
  float4 o0 = *(const float4*)(out + e);
  float4 o1 = *(const float4*)(Op + e);
  float4 r;
  r.x = (a0 * o0.x + a1 * o1.x) * inv;
  r.y = (a0 * o0.y + a1 * o1.y) * inv;
  r.z = (a0 * o0.z + a1 * o1.z) * inv;
  r.w = (a0 * o0.w + a1 * o1.w) * inv;
  *(float4*)(out + e) = r;
}

// ---------------------------------------------------------------------------
extern "C" void kernel_launch(void* const* d_in, const int* in_sizes, int n_in,
                              void* d_out, int out_size, void* d_ws,
                              size_t ws_size, hipStream_t stream) {
  const float* x   = (const float*)d_in[0];
  const float* rot = (const float*)d_in[1];
  const float* ent = (const float*)d_in[2];
  float* out = (float*)d_out;

  const size_t NE = (size_t)BATCH * SEQ * DIM;  // 16,777,216
  unsigned short* qh  = (unsigned short*)d_ws;
  unsigned short* ql  = qh + NE;
  unsigned short* kh  = ql + NE;
  unsigned short* kl  = kh + NE;
  unsigned short* xth = kl + NE;
  unsigned short* xh  = xth + NE;
  unsigned short* xl  = xh + NE;
  unsigned short* wrh = xl + NE;
  unsigned short* wrl = wrh + 262144;
  unsigned short* weh = wrl + 262144;
  unsigned short* wel = weh + 262144;
  float* Opart = (float*)(wel + 262144);  // NE floats (z=1 partial)
  float* Mp    = Opart + NE;              // 2 * 32768
  float* Lp    = Mp + 2 * (BATCH * SEQ);

  const size_t need2 =
      (7 * NE + 4 * 262144) * sizeof(unsigned short) +
      (NE + 4 * (size_t)(BATCH * SEQ)) * sizeof(float);
  const int splits = (ws_size >= need2) ? 2 : 1;

  wt_split_kernel<<<128, 256, 0, stream>>>(rot, ent, wrh, wrl, weh, wel);
  xt_split_kernel<<<dim3(SEQ / 64, DIM / 64, BATCH), 256, 0, stream>>>(x, xth, xh, xl);
  proj_both<<<dim3(BATCH * SEQ / 64, DIM / 64), 256, 0, stream>>>(
      xh, xl, wrh, wrl, weh, wel, qh, ql, kh, kl);

  attn_mfma<<<dim3(BATCH, SEQ / 32, splits), 256, 0, stream>>>(
      qh, ql, kh, kl, xth, out, Opart, Mp, Lp);
  if (splits == 2) {
    merge_kernel<<<(unsigned)(NE / 1024), 256, 0, stream>>>(out, Opart, Mp, Lp);
  }
}

// Round 3
// 1714.472 us; speedup vs baseline: 2.3671x; 1.0180x over previous
//
#include <hip/hip_runtime.h>

#define BATCH 8
#define SEQ   4096
#define DIM   512

typedef __attribute__((ext_vector_type(8))) short bf16x8;
typedef __attribute__((ext_vector_type(4))) float f32x4;

__device__ __forceinline__ unsigned short f2bf(float f) {
  unsigned int u = __float_as_uint(f);
  unsigned int r = (u + 0x7fffu + ((u >> 16) & 1u)) >> 16;
  return (unsigned short)r;
}
__device__ __forceinline__ float bf2f(unsigned short s) {
  return __uint_as_float(((unsigned int)s) << 16);
}

// async global->LDS, 16B per lane; LDS dest = wave-uniform base + lane*16
__device__ __forceinline__ void gload_lds16(const void* g, void* l) {
  __builtin_amdgcn_global_load_lds(
      (const __attribute__((address_space(1))) unsigned int*)g,
      (__attribute__((address_space(3))) unsigned int*)l, 16, 0, 0);
}

// ---------------------------------------------------------------------------
// Transpose + split weights: Wt[e][d] = W[d][e] (* scale for rotation).
// ---------------------------------------------------------------------------
__global__ __launch_bounds__(256) void wt_split_kernel(
    const float* __restrict__ rot, const float* __restrict__ ent,
    unsigned short* __restrict__ wrh, unsigned short* __restrict__ wrl,
    unsigned short* __restrict__ weh, unsigned short* __restrict__ wel) {
  const float scale = 0.04419417382415922f;  // 1/sqrt(512)
  int g = blockIdx.x * 256 + threadIdx.x;
  for (int idx = g; idx < 512 * 512; idx += 128 * 256) {
    int d = idx >> 9, e = idx & 511;
    size_t o = (size_t)e * 512 + d;
    float v = rot[idx] * scale;
    unsigned short h = f2bf(v);
    wrh[o] = h; wrl[o] = f2bf(v - bf2f(h));
    float v2 = ent[idx];
    unsigned short h2 = f2bf(v2);
    weh[o] = h2; wel[o] = f2bf(v2 - bf2f(h2));
  }
}

// ---------------------------------------------------------------------------
// Transpose x: Xt[b][d][n] = x[b][n][d], bf16 hi only (PV is single-term).
// Also emits row-major bf16 split Xh/Xl (consumed by proj_both).
// ---------------------------------------------------------------------------
__global__ __launch_bounds__(256) void xt_split_kernel(
    const float* __restrict__ X, unsigned short* __restrict__ Th,
    unsigned short* __restrict__ Xh, unsigned short* __restrict__ Xl) {
  __shared__ float T[64][65];
  const int b = blockIdx.z, n0 = blockIdx.x * 64, d0 = blockIdx.y * 64;
  const int tid = threadIdx.x;
  for (int idx = tid; idx < 4096; idx += 256) {
    int r = idx >> 6, c = idx & 63;
    size_t gi = ((size_t)(b * SEQ + n0 + r)) * DIM + d0 + c;
    float v = X[gi];
    T[r][c] = v;
    unsigned short h = f2bf(v);
    Xh[gi] = h;
    Xl[gi] = f2bf(v - bf2f(h));
  }
  __syncthreads();
  for (int idx = tid; idx < 4096; idx += 256) {
    int r = idx >> 6, c = idx & 63;  // r: d, c: n
    size_t o = ((size_t)(b * DIM + d0 + r)) * SEQ + n0 + c;
    Th[o] = f2bf(T[c][r]);
  }
}

// ---------------------------------------------------------------------------
// Fused projection: Q = X@rot*scale, K = X@ent via bf16-split MFMA (3 terms).
// ---------------------------------------------------------------------------
__global__ __launch_bounds__(256, 2) void proj_both(
    const unsigned short* __restrict__ Xh, const unsigned short* __restrict__ Xl,
    const unsigned short* __restrict__ wrh, const unsigned short* __restrict__ wrl,
    const unsigned short* __restrict__ weh, const unsigned short* __restrict__ wel,
    unsigned short* __restrict__ qh, unsigned short* __restrict__ ql,
    unsigned short* __restrict__ kh, unsigned short* __restrict__ kl) {
  const int tid = threadIdx.x;
  const int w = tid >> 6, lane = tid & 63, l15 = lane & 15, quad = lane >> 4;
  const int rowBase = blockIdx.x * 64 + (w & 1) * 32;
  const int colBase = blockIdx.y * 64 + (w >> 1) * 32;
  f32x4 qa[2][2] = {}, ka[2][2] = {};
  const unsigned short *xph[2], *xpl[2];
  const unsigned short *rh[2], *rl[2], *eh[2], *el[2];
#pragma unroll
  for (int mi = 0; mi < 2; ++mi) {
    size_t o = (size_t)(rowBase + mi * 16 + l15) * DIM + quad * 8;
    xph[mi] = Xh + o; xpl[mi] = Xl + o;
  }
#pragma unroll
  for (int ni = 0; ni < 2; ++ni) {
    size_t o = (size_t)(colBase + ni * 16 + l15) * DIM + quad * 8;
    rh[ni] = wrh + o; rl[ni] = wrl + o; eh[ni] = weh + o; el[ni] = wel + o;
  }
  for (int d0 = 0; d0 < DIM; d0 += 32) {
    bf16x8 ah[2], al[2];
#pragma unroll
    for (int mi = 0; mi < 2; ++mi) {
      ah[mi] = *(const bf16x8*)(xph[mi] + d0);
      al[mi] = *(const bf16x8*)(xpl[mi] + d0);
    }
#pragma unroll
    for (int ni = 0; ni < 2; ++ni) {
      bf16x8 bh = *(const bf16x8*)(rh[ni] + d0);
      bf16x8 bl = *(const bf16x8*)(rl[ni] + d0);
      bf16x8 ch = *(const bf16x8*)(eh[ni] + d0);
      bf16x8 cl = *(const bf16x8*)(el[ni] + d0);
#pragma unroll
      for (int mi = 0; mi < 2; ++mi) {
        qa[mi][ni] = __builtin_amdgcn_mfma_f32_16x16x32_bf16(ah[mi], bh, qa[mi][ni], 0, 0, 0);
        qa[mi][ni] = __builtin_amdgcn_mfma_f32_16x16x32_bf16(ah[mi], bl, qa[mi][ni], 0, 0, 0);
        qa[mi][ni] = __builtin_amdgcn_mfma_f32_16x16x32_bf16(al[mi], bh, qa[mi][ni], 0, 0, 0);
        ka[mi][ni] = __builtin_amdgcn_mfma_f32_16x16x32_bf16(ah[mi], ch, ka[mi][ni], 0, 0, 0);
        ka[mi][ni] = __builtin_amdgcn_mfma_f32_16x16x32_bf16(ah[mi], cl, ka[mi][ni], 0, 0, 0);
        ka[mi][ni] = __builtin_amdgcn_mfma_f32_16x16x32_bf16(al[mi], ch, ka[mi][ni], 0, 0, 0);
      }
    }
  }
#pragma unroll
  for (int mi = 0; mi < 2; ++mi)
#pragma unroll
    for (int ni = 0; ni < 2; ++ni)
#pragma unroll
      for (int r = 0; r < 4; ++r) {
        int row = rowBase + mi * 16 + quad * 4 + r;
        int col = colBase + ni * 16 + l15;
        size_t o = (size_t)row * DIM + col;
        float v = qa[mi][ni][r];
        unsigned short h = f2bf(v);
        qh[o] = h; ql[o] = f2bf(v - bf2f(h));
        float v2 = ka[mi][ni][r];
        unsigned short h2 = f2bf(v2);
        kh[o] = h2; kl[o] = f2bf(v2 - bf2f(h2));
      }
}

// ---------------------------------------------------------------------------
// Flash attention, BQ=32, BK=128, 4 waves, counted-vmcnt ring pipeline.
//   - Ring of 3 chunk slots; chunk = K(hi+lo) 16 KB + Q(hi+lo) 4 KB = 20 KB.
//     Per chunk per wave: 5 x global_load_lds (uniform count across waves).
//   - Main loop NEVER drains vmcnt: s_waitcnt vmcnt(5) certifies the current
//     chunk (the next stays in flight), raw s_barrier (no drain), then issue
//     chunk c+2 into slot (c+2)%3 (WAR-safe: that slot's last readers passed
//     this barrier).  Q must ride the LDS ring: a direct global Q load would
//     poison the in-order vmcnt FIFO (waiting on it drains the prefetch).
//   - PsH separate (8 KB) -> next-iter chunks 0-1 prefetch during softmax/PV.
//   - Softmax barriers: raw s_barrier + explicit lgkmcnt(0) + sched_barrier.
//   - setprio(1) around MFMA clusters (T5; phase-split now exists).
//   - LDS = 71 KB -> 2 blocks/CU.
// ---------------------------------------------------------------------------
__global__ __launch_bounds__(256, 2) void attn_mfma(
    const unsigned short* __restrict__ Qh, const unsigned short* __restrict__ Ql,
    const unsigned short* __restrict__ Kh, const unsigned short* __restrict__ Kl,
    const unsigned short* __restrict__ Xth, float* __restrict__ out,
    float* __restrict__ Opart, float* __restrict__ Mp, float* __restrict__ Lp) {
  // slot layout (shorts): [0,4096) Kh 128x32 | [4096,8192) Kl | [8192,10240) Q hi+lo
  __shared__ short ring[3][10240];             // 60 KiB
  __shared__ unsigned short PsH[32 * 128];     // 8 KiB, XOR-swizzled
  __shared__ float red1[32][2], red2[32][2], al_s[32], l_s[32];

  const int tid = threadIdx.x;
  const int w = tid >> 6, lane = tid & 63, l15 = lane & 15, quad = lane >> 4;
  const int wq = w & 1, wk = w >> 1;
  const int b = blockIdx.x, q0 = blockIdx.y * 32;
  const int iters = (SEQ / 128) / gridDim.z;
  const int NC = iters * 16;
  const int kbase = blockIdx.z * iters * 128;
  const int dbase = w * 128;  // PV output d-slice per wave

  // ---- staging source maps (pre-swizzled global, linear LDS) ----
  const int r0 = tid >> 2;                    // K row within 64-row half
  const int clogK = (tid & 3) ^ (r0 & 3);
  const unsigned short* kplane[2] = {Kh + (size_t)b * SEQ * DIM,
                                     Kl + (size_t)b * SEQ * DIM};
  const int qrow = (tid >> 2) & 31;
  const int clogQ = (tid & 3) ^ (qrow & 3);
  const unsigned short* qsrc =
      ((tid >> 7) ? Ql : Qh) + (size_t)(b * SEQ + q0 + qrow) * DIM + clogQ * 8;

  auto STAGE = [&](int slot, int krow0, int cc) {
    short* base = &ring[slot][0];
#pragma unroll
    for (int j = 0; j < 4; ++j) {
      gload_lds16(
          kplane[j >> 1] + (size_t)(krow0 + (j & 1) * 64 + r0) * DIM + cc * 32 + clogK * 8,
          base + j * 2048 + w * 512);
    }
    gload_lds16(qsrc + cc * 32, base + 8192 + w * 512);
  };

  f32x4 Of[2][8] = {};
  float m_r[4], l_r[4];
#pragma unroll
  for (int r = 0; r < 4; ++r) { m_r[r] = -3.0e38f; l_r[r] = 0.0f; }

  // prologue: chunks 0,1 -> slots 0,1
  STAGE(0, kbase, 0);
  STAGE(1, kbase, 1);

  int sl = 0;  // ring slot of the current chunk
  for (int t = 0; t < iters; ++t) {
    const int k0 = kbase + t * 128;
    f32x4 sa[4] = {};

    // ---- S = Q K^T over 16 chunks of 32 d, 3-slot ring, counted vmcnt ----
#pragma unroll
    for (int c = 0; c < 16; ++c) {
      if (t == iters - 1 && c == 15) {
        asm volatile("s_waitcnt vmcnt(0)" ::: "memory");   // final chunk only
      } else {
        asm volatile("s_waitcnt vmcnt(5)" ::: "memory");   // certify chunk c
      }
      __builtin_amdgcn_sched_barrier(0);
      __builtin_amdgcn_s_barrier();        // rendezvous, no drain
      // issue chunk c+2
      {
        const int gn = t * 16 + c + 2;
        if (gn < NC) {
          int slot2 = sl + 2; if (slot2 >= 3) slot2 -= 3;
          STAGE(slot2, kbase + (gn >> 4) * 128, gn & 15);
        }
      }
      const short* base = &ring[sl][0];
      const int cq = (quad ^ (l15 & 3)) * 8;
      bf16x8 ah = *(const bf16x8*)(base + 8192 + (wq * 16 + l15) * 32 + cq);
      bf16x8 al = *(const bf16x8*)(base + 9216 + (wq * 16 + l15) * 32 + cq);
      __builtin_amdgcn_s_setprio(1);
#pragma unroll
      for (int s = 0; s < 4; ++s) {
        const int kr = wk * 64 + s * 16 + l15;
        bf16x8 bh = *(const bf16x8*)(base + kr * 32 + cq);
        bf16x8 bl = *(const bf16x8*)(base + 4096 + kr * 32 + cq);
        sa[s] = __builtin_amdgcn_mfma_f32_16x16x32_bf16(ah, bh, sa[s], 0, 0, 0);
        sa[s] = __builtin_amdgcn_mfma_f32_16x16x32_bf16(ah, bl, sa[s], 0, 0, 0);
        sa[s] = __builtin_amdgcn_mfma_f32_16x16x32_bf16(al, bh, sa[s], 0, 0, 0);
      }
      __builtin_amdgcn_s_setprio(0);
      sl = (sl + 1 == 3) ? 0 : sl + 1;
    }

    // ---- online softmax: wave owns rows wq*16 + quad*4 + r (k-half wk) ----
    float pm[4];
#pragma unroll
    for (int r = 0; r < 4; ++r) {
      float v = fmaxf(fmaxf(sa[0][r], sa[1][r]), fmaxf(sa[2][r], sa[3][r]));
#pragma unroll
      for (int off = 1; off < 16; off <<= 1) v = fmaxf(v, __shfl_xor(v, off, 64));
      pm[r] = v;
    }
    if (l15 == 0) {
#pragma unroll
      for (int r = 0; r < 4; ++r) red1[wq * 16 + quad * 4 + r][wk] = pm[r];
    }
    asm volatile("s_waitcnt lgkmcnt(0)" ::: "memory");
    __builtin_amdgcn_sched_barrier(0);
    __builtin_amdgcn_s_barrier();  // B1
    float al_r[4];
#pragma unroll
    for (int r = 0; r < 4; ++r) {
      const int row = wq * 16 + quad * 4 + r;
      float mn = fmaxf(m_r[r], fmaxf(red1[row][0], red1[row][1]));
      al_r[r] = __expf(m_r[r] - mn);
      m_r[r] = mn;
    }
#pragma unroll
    for (int r = 0; r < 4; ++r) {
      const int row = wq * 16 + quad * 4 + r, rx = row & 15;
      float sum = 0.0f;
#pragma unroll
      for (int s = 0; s < 4; ++s) {
        float p = __expf(sa[s][r] - m_r[r]);
        sum += p;
        const int col = wk * 64 + s * 16 + l15;
        PsH[row * 128 + ((col >> 3) ^ rx) * 8 + (col & 7)] = f2bf(p);
      }
#pragma unroll
      for (int off = 1; off < 16; off <<= 1) sum += __shfl_xor(sum, off, 64);
      if (l15 == 0) {
        red2[row][wk] = sum;
        if (wk == 0) al_s[row] = al_r[r];
      }
    }
    asm volatile("s_waitcnt lgkmcnt(0)" ::: "memory");
    __builtin_amdgcn_sched_barrier(0);
    __builtin_amdgcn_s_barrier();  // B2
#pragma unroll
    for (int r = 0; r < 4; ++r) {
      const int row = wq * 16 + quad * 4 + r;
      l_r[r] = l_r[r] * al_r[r] + red2[row][0] + red2[row][1];
    }

    // ---- O = O*alpha + P @ x ; wave d-slice [dbase, dbase+128) ----
    float alv[2][4];
#pragma unroll
    for (int qt = 0; qt < 2; ++qt)
#pragma unroll
      for (int r = 0; r < 4; ++r) alv[qt][r] = al_s[qt * 16 + quad * 4 + r];
#pragma unroll
    for (int qt = 0; qt < 2; ++qt)
#pragma unroll
      for (int nt = 0; nt < 8; ++nt)
#pragma unroll
        for (int r = 0; r < 4; ++r) Of[qt][nt][r] *= alv[qt][r];

    const unsigned short* Xb =
        Xth + ((size_t)(b * DIM + dbase) + l15) * SEQ + k0 + quad * 8;
#pragma unroll
    for (int ks = 0; ks < 4; ++ks) {
      bf16x8 Ph[2];
#pragma unroll
      for (int qt = 0; qt < 2; ++qt) {
        const int prow = qt * 16 + l15;
        const int sb = (ks * 4 + quad) ^ l15;
        Ph[qt] = *(const bf16x8*)(PsH + prow * 128 + sb * 8);
      }
#pragma unroll
      for (int nh = 0; nh < 2; ++nh) {
        bf16x8 xf[4];
#pragma unroll
        for (int i = 0; i < 4; ++i)
          xf[i] = *(const bf16x8*)(Xb + (size_t)((nh * 4 + i) * 16) * SEQ + ks * 32);
        __builtin_amdgcn_s_setprio(1);
#pragma unroll
        for (int i = 0; i < 4; ++i)
#pragma unroll
          for (int qt = 0; qt < 2; ++qt)
            Of[qt][nh * 4 + i] = __builtin_amdgcn_mfma_f32_16x16x32_bf16(
                Ph[qt], xf[i], Of[qt][nh * 4 + i], 0, 0, 0);
        __builtin_amdgcn_s_setprio(0);
      }
    }
    // no B3: PsH/red/al_s next written only after next iter's B1/B2, which
    // every wave reaches only after all waves finish this PV (barrier gating).
  }

  // ---- epilogue ----
  if (wk == 0 && l15 == 0) {
#pragma unroll
    for (int r = 0; r < 4; ++r) l_s[wq * 16 + quad * 4 + r] = l_r[r];
    if (gridDim.z > 1) {
      size_t ri = (size_t)blockIdx.z * (BATCH * SEQ) + (size_t)b * SEQ + q0 +
                  wq * 16 + quad * 4;
#pragma unroll
      for (int r = 0; r < 4; ++r) { Mp[ri + r] = m_r[r]; Lp[ri + r] = l_r[r]; }
    }
  }
  __syncthreads();

  if (gridDim.z == 1) {
    float inv[2][4];
#pragma unroll
    for (int qt = 0; qt < 2; ++qt)
#pragma unroll
      for (int r = 0; r < 4; ++r) inv[qt][r] = 1.0f / l_s[qt * 16 + quad * 4 + r];
#pragma unroll
    for (int qt = 0; qt < 2; ++qt)
#pragma unroll
      for (int r = 0; r < 4; ++r) {
        const size_t ro =
            ((size_t)(b * SEQ + q0 + qt * 16 + quad * 4 + r)) * DIM + dbase;
#pragma unroll
        for (int nt = 0; nt < 8; ++nt)
          out[ro + nt * 16 + l15] = Of[qt][nt][r] * inv[qt][r];
      }
  } else {
    float* Ob = (blockIdx.z == 0) ? out : Opart;
#pragma unroll
    for (int qt = 0; qt < 2; ++qt)
#pragma unroll
      for (int r = 0; r < 4; ++r) {
        const size_t ro =
            ((size_t)(b * SEQ + q0 + qt * 16 + quad * 4 + r)) * DIM + dbase;
#pragma unroll
        for (int nt = 0; nt < 8; ++nt) Ob[ro + nt * 16 + l15] = Of[qt][nt][r];
      }
  }
}

// ---------------------------------------------------------------------------
// Merge split-K partials: z=0 partial lives in `out`, z=1 in Opart.
// ---------------------------------------------------------------------------
__global__ __launch_bounds__(256) void merge_kernel(
    float* __restrict__ out, const float* __restrict__ Op,
    const float* __restrict__ Mp, const float* __restrict__ Lp) {
  const int NR = BATCH * SEQ;
  size_t e = ((size_t)blockIdx.x * 256 + threadIdx.x) * 4;
  int row = (int)(e >> 9);
  float m0 = Mp[row], m1 = Mp[NR + row];
  float l0 = Lp[row], l1 = Lp[NR + row];
  float m = fmaxf(m0, m1);
  float a0 = __expf(m0 - m), a1 = __expf(m1 - m);
  float inv = 1.0f / (a0 * l0 + a1 * l1);
  float4 o0 = *(const float4*)(out + e);
  float4 o1 = *(const float4*)(Op + e);
  float4 r;
  r.x = (a0 * o0.x + a1 * o1.x) * inv;
  r.y = (a0 * o0.y + a1 * o1.y) * inv;
  r.z = (a0 * o0.z + a1 * o1.z) * inv;
  r.w = (a0 * o0.w + a1 * o1.w) * inv;
  *(float4*)(out + e) = r;
}

// ---------------------------------------------------------------------------
extern "C" void kernel_launch(void* const* d_in, const int* in_sizes, int n_in,
                              void* d_out, int out_size, void* d_ws,
                              size_t ws_size, hipStream_t stream) {
  const float* x   = (const float*)d_in[0];
  const float* rot = (const float*)d_in[1];
  const float* ent = (const float*)d_in[2];
  float* out = (float*)d_out;

  const size_t NE = (size_t)BATCH * SEQ * DIM;  // 16,777,216
  unsigned short* qh  = (unsigned short*)d_ws;
  unsigned short* ql  = qh + NE;
  unsigned short* kh  = ql + NE;
  unsigned short* kl  = kh + NE;
  unsigned short* xth = kl + NE;
  unsigned short* xh  = xth + NE;
  unsigned short* xl  = xh + NE;
  unsigned short* wrh = xl + NE;
  unsigned short* wrl = wrh + 262144;
  unsigned short* weh = wrl + 262144;
  unsigned short* wel = weh + 262144;
  float* Opart = (float*)(wel + 262144);  // NE floats (z=1 partial)
  float* Mp    = Opart + NE;              // 2 * 32768
  float* Lp    = Mp + 2 * (BATCH * SEQ);

  const size_t need2 =
      (7 * NE + 4 * 262144) * sizeof(unsigned short) +
      (NE + 4 * (size_t)(BATCH * SEQ)) * sizeof(float);
  const int splits = (ws_size >= need2) ? 2 : 1;

  wt_split_kernel<<<128, 256, 0, stream>>>(rot, ent, wrh, wrl, weh, wel);
  xt_split_kernel<<<dim3(SEQ / 64, DIM / 64, BATCH), 256, 0, stream>>>(x, xth, xh, xl);
  proj_both<<<dim3(BATCH * SEQ / 64, DIM / 64), 256, 0, stream>>>(
      xh, xl, wrh, wrl, weh, wel, qh, ql, kh, kl);

  attn_mfma<<<dim3(BATCH, SEQ / 32, splits), 256, 0, stream>>>(
      qh, ql, kh, kl, xth, out, Opart, Mp, Lp);
  if (splits == 2) {
    merge_kernel<<<(unsigned)(NE / 1024), 256, 0, stream>>>(out, Opart, Mp, Lp);
  }
}